// Round 9
// baseline (169.905 us; speedup 1.0000x reference)
//
#include <hip/hip_runtime.h>
#include <stdint.h>

typedef int v4i __attribute__((ext_vector_type(4)));
typedef float float4_t __attribute__((ext_vector_type(4)));

#define K_DIM 1024
#define N_DIM 1024
#define BM 128
#define BN 128

__device__ __forceinline__ void gload16(const void* g, void* l) {
  __builtin_amdgcn_global_load_lds(
      (const __attribute__((address_space(1))) unsigned int*)g,
      (__attribute__((address_space(3))) unsigned int*)l, 16, 0, 0);
}

#define MFMA_I8 __builtin_amdgcn_mfma_i32_16x16x64_i8

// ---------------------------------------------------------------------------
// Kernel 1: per-token FWHT (== x @ H, H = Sylvester/sqrt(1024)) + 4-bit quant.
// 1 wave/token, 16 f32/lane, mapping e = lane*16 + r. (unchanged from R8)
// ---------------------------------------------------------------------------
__global__ __launch_bounds__(256) void fwht_quant_kernel(
    const float* __restrict__ x, int8_t* __restrict__ qx,
    float* __restrict__ ascale, int M) {
  const int lane = threadIdx.x & 63;
  const int wid = threadIdx.x >> 6;
  const long token = (long)blockIdx.x * 4 + wid;
  if (token >= M) return;
  const float4_t* xr4 = (const float4_t*)(x + token * K_DIM);

  float v[16];
#pragma unroll
  for (int i = 0; i < 4; ++i) {
    float4_t f = xr4[lane * 4 + i];
#pragma unroll
    for (int c = 0; c < 4; ++c) v[i * 4 + c] = f[c];
  }
#pragma unroll
  for (int s = 1; s <= 8; s <<= 1) {
#pragma unroll
    for (int r = 0; r < 16; ++r)
      if ((r & s) == 0) {
        float a0 = v[r], b0 = v[r | s];
        v[r] = a0 + b0;
        v[r | s] = a0 - b0;
      }
  }
#pragma unroll
  for (int m = 1; m <= 32; m <<= 1) {
    const float sg = (lane & m) ? -1.0f : 1.0f;
#pragma unroll
    for (int r = 0; r < 16; ++r) {
      float p = __shfl_xor(v[r], m, 64);
      v[r] = fmaf(sg, v[r], p);
    }
  }
  float mx = 0.f;
#pragma unroll
  for (int r = 0; r < 16; ++r) mx = fmaxf(mx, fabsf(v[r]));
#pragma unroll
  for (int m = 32; m >= 1; m >>= 1) mx = fmaxf(mx, __shfl_xor(mx, m, 64));
  const float scale = fmaxf(mx * 0.03125f, 1e-5f) * (1.0f / 7.0f);
  if (lane == 0) ascale[token] = scale;
  const float inv = 0.03125f / scale;

  v4i pk;
#pragma unroll
  for (int i = 0; i < 4; ++i) {
    int packed = 0;
#pragma unroll
    for (int c = 0; c < 4; ++c) {
      float q = rintf(v[i * 4 + c] * inv);
      q = fminf(7.f, fmaxf(-8.f, q));
      packed |= ((int)q & 0xff) << (8 * c);
    }
    pk[i] = packed;
  }
  *(v4i*)(qx + token * K_DIM + lane * 16) = pk;
}

// ---------------------------------------------------------------------------
// Kernel 2: per-row ternary weight quantization. 1 wave per row. (unchanged)
// ---------------------------------------------------------------------------
__global__ __launch_bounds__(256) void wquant_kernel(
    const float* __restrict__ w, int8_t* __restrict__ qw,
    float* __restrict__ wscale) {
  const int lane = threadIdx.x & 63;
  const int wid = threadIdx.x >> 6;
  const int row = blockIdx.x * 4 + wid;
  const float* wr = w + (long)row * K_DIM;

  float v[16];
  float s = 0.f;
  const float4_t* wr4 = (const float4_t*)wr;
#pragma unroll
  for (int rr = 0; rr < 4; ++rr) {
    float4_t f = wr4[rr * 64 + lane];
#pragma unroll
    for (int c = 0; c < 4; ++c) {
      v[rr * 4 + c] = f[c];
      s += fabsf(f[c]);
    }
  }
#pragma unroll
  for (int m = 32; m >= 1; m >>= 1) s += __shfl_xor(s, m, 64);
  const float scale = fmaxf(s * (1.0f / 1024.0f), 1e-5f);
  if (lane == 0) wscale[row] = scale;

  int8_t* qr = qw + (long)row * K_DIM;
#pragma unroll
  for (int rr = 0; rr < 4; ++rr) {
    int packed = 0;
#pragma unroll
    for (int c = 0; c < 4; ++c) {
      float n = v[rr * 4 + c] / scale;
      int t = (n > 0.5f) ? 1 : ((n < -0.5f) ? -1 : 0);
      packed |= (t & 0xff) << (8 * c);
    }
    *(int*)(qr + rr * 256 + lane * 4) = packed;
  }
}

// ---------------------------------------------------------------------------
// Kernel 3: int8 GEMM, 128x128 tile, BK=128, 4 waves.
// R9 change (one variable): asymmetric counted-vmcnt pipeline.
//  - A (HBM-latency ~900cy): 3 buffers, staged 2 K-tiles ahead.
//  - B (L2-hot, 1MB):        2 buffers, staged 1 K-tile ahead.
//  - Per kt: ds_reads(cur); STAGE_B(kt+1); STAGE_A(kt+2); MFMA;
//    vmcnt(4) <- only A(kt+2) (the newest 4 loads) may remain in flight;
//    raw s_barrier. Never drains to 0 until the tail (T4).
//  - LDS 3*16+2*16 = 80 KB -> still 2 blocks/CU (epilogue overlap kept).
// Kept (proven): T1 XCD swizzle, chunk-XOR LDS swizzle, LDS-transpose
// epilogue w/ full-line float4 nt stores, tr stride 132.
// ---------------------------------------------------------------------------
__global__ __launch_bounds__(256) void gemm_i8_kernel(
    const int8_t* __restrict__ A, const int8_t* __restrict__ B,
    const float* __restrict__ asc, const float* __restrict__ wsc,
    float* __restrict__ C, int M) {
  __shared__ __align__(16) int8_t Abuf[3][16384];
  __shared__ __align__(16) int8_t Bbuf[2][16384];
  float* tr = (float*)Abuf;  // epilogue: 64 rows x 132 f32 = 33792 B

  const int t = threadIdx.x;
  const int lane = t & 63;
  const int wm = (t >> 6) >> 1;
  const int wn = (t >> 6) & 1;
  const int rl = lane & 15;
  const int kb = lane >> 4;

  // T1: XCD swizzle. grid=4096 (%8==0): bm chunk per XCD, bn fastest.
  const int swz = ((int)blockIdx.x & 7) * 512 + ((int)blockIdx.x >> 3);
  const long bm = swz >> 3;  // 0..511
  const int bn = swz & 7;    // 0..7

  // staging: stmt s covers rows s*32 + (t>>3); phys slot t&7 holds logical
  // chunk (t&7)^(row&7). LDS dest linear (rule #21).
  const int chunkoff = (((t & 7) ^ ((t >> 3) & 7)) << 4);
  const int8_t* gA = A + (bm * BM + (t >> 3)) * (long)K_DIM + chunkoff;
  const int8_t* gB = B + ((long)bn * BN + (t >> 3)) * K_DIM + chunkoff;

  // frag reads: logical chunk ks2*4+kb at row (..+rl) -> phys ^(rl&7)
  const int sw0 = ((kb ^ (rl & 7)) << 4);
  const int sw1 = (((4 + kb) ^ (rl & 7)) << 4);
  const int arow = (wm * 64 + rl) * 128;
  const int brow = (wn * 64 + rl) * 128;

  v4i acc[4][4] = {};

#define STAGE_A(p, ks)                                     \
  gload16(gA + (ks), Abuf[p] + t * 16);                    \
  gload16(gA + (ks) + 32 * K_DIM, Abuf[p] + 4096 + t * 16); \
  gload16(gA + (ks) + 64 * K_DIM, Abuf[p] + 8192 + t * 16); \
  gload16(gA + (ks) + 96 * K_DIM, Abuf[p] + 12288 + t * 16);
#define STAGE_B(p, ks)                                     \
  gload16(gB + (ks), Bbuf[p] + t * 16);                    \
  gload16(gB + (ks) + 32 * K_DIM, Bbuf[p] + 4096 + t * 16); \
  gload16(gB + (ks) + 64 * K_DIM, Bbuf[p] + 8192 + t * 16); \
  gload16(gB + (ks) + 96 * K_DIM, Bbuf[p] + 12288 + t * 16);

  // prologue: A0, B0, A1 (issue order matters for vmcnt counting)
  STAGE_A(0, 0);
  STAGE_B(0, 0);
  STAGE_A(1, 128);
  asm volatile("s_waitcnt vmcnt(4)" ::: "memory");  // A0,B0 landed; A1 flying
  asm volatile("s_barrier" ::: "memory");

#pragma unroll
  for (int kt = 0; kt < 8; ++kt) {
    const int p3 = kt % 3;       // A buffer
    const int p2 = kt & 1;       // B buffer
    const int8_t* Al = Abuf[p3];
    const int8_t* Bl = Bbuf[p2];

    // prefetch: B first (must land by next barrier), then A (2 ahead,
    // stays in flight across the barrier -> the newest 4 at the wait).
    if (kt < 7) {
      STAGE_B((kt + 1) & 1, (kt + 1) * 128);
    }
    if (kt < 6) {
      STAGE_A((kt + 2) % 3, (kt + 2) * 128);
    }

#pragma unroll
    for (int ks2 = 0; ks2 < 2; ++ks2) {
      const int sw = ks2 ? sw1 : sw0;
      v4i a[4], b[4];
#pragma unroll
      for (int i = 0; i < 4; ++i)
        a[i] = *(const v4i*)(Al + arow + i * 2048 + sw);
#pragma unroll
      for (int j = 0; j < 4; ++j)
        b[j] = *(const v4i*)(Bl + brow + j * 2048 + sw);
#pragma unroll
      for (int i = 0; i < 4; ++i)
#pragma unroll
        for (int j = 0; j < 4; ++j)
          acc[i][j] = MFMA_I8(a[i], b[j], acc[i][j], 0, 0, 0);
    }

    // counted waits (T4): leave A(kt+2) in flight; everything older landed.
    if (kt < 6) {
      asm volatile("s_waitcnt vmcnt(4)" ::: "memory");
      asm volatile("s_barrier" ::: "memory");
    } else if (kt == 6) {
      asm volatile("s_waitcnt vmcnt(0)" ::: "memory");
      asm volatile("s_barrier" ::: "memory");
    }
  }
#undef STAGE_A
#undef STAGE_B

  __syncthreads();  // all LDS reads retired before tr aliases Abuf

  // ---- LDS-transpose epilogue, 2 chunks of 64 rows, tr stride 132 ----
  const long rowg0 = bm * BM + wm * 64;
  const int colg0 = bn * BN + wn * 64;
#pragma unroll
  for (int c = 0; c < 2; ++c) {
    if (wm == c) {
#pragma unroll
      for (int i = 0; i < 4; ++i) {
        float as[4];
#pragma unroll
        for (int r = 0; r < 4; ++r) as[r] = asc[rowg0 + i * 16 + kb * 4 + r];
#pragma unroll
        for (int j = 0; j < 4; ++j) {
          const float ws = wsc[colg0 + j * 16 + rl];
#pragma unroll
          for (int r = 0; r < 4; ++r)
            tr[(i * 16 + kb * 4 + r) * 132 + wn * 64 + j * 16 + rl] =
                (float)acc[i][j][r] * as[r] * ws;
        }
      }
    }
    __syncthreads();
    // 256 threads x 8 float4 nt stores: 32 lanes cover 512B = 4 full lines
#pragma unroll
    for (int it = 0; it < 8; ++it) {
      const int idx = t + it * 256;   // 0..2047
      const int rl2 = idx >> 5;       // local row 0..63
      const int c4 = (idx & 31) * 4;  // col in floats
      const float4_t val = *(const float4_t*)(tr + rl2 * 132 + c4);
      __builtin_nontemporal_store(
          val, (float4_t*)(C + (bm * BM + c * 64 + rl2) * (long)N_DIM + bn * BN + c4));
    }
    if (c == 0) __syncthreads();  // tr reused by chunk 1
  }
}

// ---------------------------------------------------------------------------
extern "C" void kernel_launch(void* const* d_in, const int* in_sizes, int n_in,
                              void* d_out, int out_size, void* d_ws, size_t ws_size,
                              hipStream_t stream) {
  const float* x = (const float*)d_in[0];  // [8,8192,1024] f32
  const float* w = (const float*)d_in[1];  // [1024,1024] f32
  float* out = (float*)d_out;              // [8,8192,1024] f32
  const int M = in_sizes[0] / K_DIM;       // 65536

  int8_t* qx = (int8_t*)d_ws;
  int8_t* qw = qx + (size_t)M * K_DIM;
  float* ascale = (float*)(qw + (size_t)N_DIM * K_DIM);
  float* wscale = ascale + M;

  fwht_quant_kernel<<<(M + 3) / 4, 256, 0, stream>>>(x, qx, ascale, M);
  wquant_kernel<<<N_DIM / 4, 256, 0, stream>>>(w, qw, wscale);
  gemm_i8_kernel<<<(M / BM) * (N_DIM / BN), 256, 0, stream>>>(qx, qw, ascale, wscale, out, M);
}

// Round 10
// 168.302 us; speedup vs baseline: 1.0095x; 1.0095x over previous
//
#include <hip/hip_runtime.h>
#include <stdint.h>

typedef int v4i __attribute__((ext_vector_type(4)));
typedef float float4_t __attribute__((ext_vector_type(4)));

#define K_DIM 1024
#define N_DIM 1024
#define BM 256
#define BN 256
#define NKT 8

__device__ __forceinline__ void gload16(const void* g, void* l) {
  __builtin_amdgcn_global_load_lds(
      (const __attribute__((address_space(1))) unsigned int*)g,
      (__attribute__((address_space(3))) unsigned int*)l, 16, 0, 0);
}

#define MFMA_I8 __builtin_amdgcn_mfma_i32_16x16x64_i8

// ---------------------------------------------------------------------------
// Kernel 1: per-token FWHT (== x @ H, H = Sylvester/sqrt(1024)) + 4-bit quant.
// 1 wave/token, 16 f32/lane, mapping e = lane*16 + r. (unchanged from R8)
// ---------------------------------------------------------------------------
__global__ __launch_bounds__(256) void fwht_quant_kernel(
    const float* __restrict__ x, int8_t* __restrict__ qx,
    float* __restrict__ ascale, int M) {
  const int lane = threadIdx.x & 63;
  const int wid = threadIdx.x >> 6;
  const long token = (long)blockIdx.x * 4 + wid;
  if (token >= M) return;
  const float4_t* xr4 = (const float4_t*)(x + token * K_DIM);

  float v[16];
#pragma unroll
  for (int i = 0; i < 4; ++i) {
    float4_t f = xr4[lane * 4 + i];
#pragma unroll
    for (int c = 0; c < 4; ++c) v[i * 4 + c] = f[c];
  }
#pragma unroll
  for (int s = 1; s <= 8; s <<= 1) {
#pragma unroll
    for (int r = 0; r < 16; ++r)
      if ((r & s) == 0) {
        float a0 = v[r], b0 = v[r | s];
        v[r] = a0 + b0;
        v[r | s] = a0 - b0;
      }
  }
#pragma unroll
  for (int m = 1; m <= 32; m <<= 1) {
    const float sg = (lane & m) ? -1.0f : 1.0f;
#pragma unroll
    for (int r = 0; r < 16; ++r) {
      float p = __shfl_xor(v[r], m, 64);
      v[r] = fmaf(sg, v[r], p);
    }
  }
  float mx = 0.f;
#pragma unroll
  for (int r = 0; r < 16; ++r) mx = fmaxf(mx, fabsf(v[r]));
#pragma unroll
  for (int m = 32; m >= 1; m >>= 1) mx = fmaxf(mx, __shfl_xor(mx, m, 64));
  const float scale = fmaxf(mx * 0.03125f, 1e-5f) * (1.0f / 7.0f);
  if (lane == 0) ascale[token] = scale;
  const float inv = 0.03125f / scale;

  v4i pk;
#pragma unroll
  for (int i = 0; i < 4; ++i) {
    int packed = 0;
#pragma unroll
    for (int c = 0; c < 4; ++c) {
      float q = rintf(v[i * 4 + c] * inv);
      q = fminf(7.f, fmaxf(-8.f, q));
      packed |= ((int)q & 0xff) << (8 * c);
    }
    pk[i] = packed;
  }
  *(v4i*)(qx + token * K_DIM + lane * 16) = pk;
}

// ---------------------------------------------------------------------------
// Kernel 2: per-row ternary weight quantization. 1 wave per row. (unchanged)
// ---------------------------------------------------------------------------
__global__ __launch_bounds__(256) void wquant_kernel(
    const float* __restrict__ w, int8_t* __restrict__ qw,
    float* __restrict__ wscale) {
  const int lane = threadIdx.x & 63;
  const int wid = threadIdx.x >> 6;
  const int row = blockIdx.x * 4 + wid;
  const float* wr = w + (long)row * K_DIM;

  float v[16];
  float s = 0.f;
  const float4_t* wr4 = (const float4_t*)wr;
#pragma unroll
  for (int rr = 0; rr < 4; ++rr) {
    float4_t f = wr4[rr * 64 + lane];
#pragma unroll
    for (int c = 0; c < 4; ++c) {
      v[rr * 4 + c] = f[c];
      s += fabsf(f[c]);
    }
  }
#pragma unroll
  for (int m = 32; m >= 1; m >>= 1) s += __shfl_xor(s, m, 64);
  const float scale = fmaxf(s * (1.0f / 1024.0f), 1e-5f);
  if (lane == 0) wscale[row] = scale;

  int8_t* qr = qw + (long)row * K_DIM;
#pragma unroll
  for (int rr = 0; rr < 4; ++rr) {
    int packed = 0;
#pragma unroll
    for (int c = 0; c < 4; ++c) {
      float n = v[rr * 4 + c] / scale;
      int t = (n > 0.5f) ? 1 : ((n < -0.5f) ? -1 : 0);
      packed |= (t & 0xff) << (8 * c);
    }
    *(int*)(qr + rr * 256 + lane * 4) = packed;
  }
}

// ---------------------------------------------------------------------------
// Kernel 3: int8 GEMM, 256x256 tile, 8 waves (2Mx4N, wave=128x64), 8-phase
// K-loop (R3 skeleton, ran bit-exact) on the R7/R8 clean memory path.
// Why: K-loop is DS-throughput-bound (16 ds_read_b128 x 12cy x 4 waves =
// 768 cyc/kt vs 146 cyc MFMA at 128^2). 256^2 cuts LDS bytes/output-elem
// 4 -> 2.93 and halves block count -> DS ~55 -> ~43 us; 8-phase interleaves
// DS with MFMA. LDS 128KB double-buffered -> 1 block/CU (512 thr).
//  - T1 XCD swizzle (grid 1024 % 8 == 0): bm chunk per XCD, bn fastest.
//  - chunk-XOR LDS swizzle both operands (rule #21, 0 conflicts).
//  - 4-chunk LDS-transpose epilogue, full-line float4 nt stores (tr str 260).
// ---------------------------------------------------------------------------
__global__ __launch_bounds__(512) void gemm_i8_kernel(
    const int8_t* __restrict__ A, const int8_t* __restrict__ B,
    const float* __restrict__ asc, const float* __restrict__ wsc,
    float* __restrict__ C, int M) {
  __shared__ __align__(16) int8_t Al[2][BM * 128];
  __shared__ __align__(16) int8_t Bl[2][BN * 128];
  float* tr = (float*)Al;  // epilogue: 64 rows x 260 f32 = 66560 B (alias)

  const int t = threadIdx.x;
  const int lane = t & 63;
  const int wid = t >> 6;
  const int wm = wid >> 2;  // 0..1
  const int wn = wid & 3;   // 0..3
  const int rl = lane & 15;
  const int kb = lane >> 4;

  // T1: XCD swizzle. grid=1024 (%8==0). XCD x: swz [x*128, x*128+127] ->
  // bm chunk of 32 with bn fastest: A-tile fetched once per XCD L2.
  const int swz = ((int)blockIdx.x & 7) * 128 + ((int)blockIdx.x >> 3);
  const long bm = swz >> 2;  // 0..255
  const int bn = swz & 3;    // 0..3

  // staging: stmt s covers rows s*64 + (t>>3); phys slot t&7 holds logical
  // chunk (t&7)^(row&7). LDS dest linear (rule #21).
  const int chunkoff = (((t & 7) ^ ((t >> 3) & 7)) << 4);
  const int8_t* gA = A + (bm * BM + (t >> 3)) * (long)K_DIM + chunkoff;
  const int8_t* gB = B + ((long)bn * BN + (t >> 3)) * K_DIM + chunkoff;

  // frag reads: logical chunk ks2*4+kb at row (..+rl) -> phys ^(rl&7)
  const int sw0 = ((kb ^ (rl & 7)) << 4);
  const int sw1 = (((4 + kb) ^ (rl & 7)) << 4);
  const int aoff = (wm * 128 + rl) * 128;
  const int boff = (wn * 64 + rl) * 128;

  v4i acc[8][4] = {};

#define STAGE4(gbase, buf, koff)                                   \
  gload16((gbase) + (koff), (buf) + t * 16);                       \
  gload16((gbase) + 64 * K_DIM + (koff), (buf) + 8192 + t * 16);   \
  gload16((gbase) + 128 * K_DIM + (koff), (buf) + 16384 + t * 16); \
  gload16((gbase) + 192 * K_DIM + (koff), (buf) + 24576 + t * 16);

  // prologue: stage tiles 0 and 1 (16 gloads/thread-group)
  STAGE4(gA, &Al[0][0], 0);
  STAGE4(gB, &Bl[0][0], 0);
  STAGE4(gA, &Al[1][0], 128);
  STAGE4(gB, &Bl[1][0], 128);
  asm volatile("s_waitcnt vmcnt(8)" ::: "memory");  // tile0 landed
  asm volatile("s_barrier" ::: "memory");

  for (int kt = 0; kt < NKT; ++kt) {
    const int p = kt & 1;
    const int8_t* Ab = &Al[p][0];
    const int8_t* Bb = &Bl[p][0];
    const bool pre = (kt + 2) < NKT;
    const int kfo = (kt + 2) * 128;

    v4i b[4][2], a[2][2];

    // ---- phase 0: all B frags + A f0,f1; MFMA quadrant 0
#pragma unroll
    for (int n = 0; n < 4; ++n) {
      b[n][0] = *(const v4i*)(Bb + n * 2048 + boff + sw0);
      b[n][1] = *(const v4i*)(Bb + n * 2048 + boff + sw1);
    }
#pragma unroll
    for (int f = 0; f < 2; ++f) {
      a[f][0] = *(const v4i*)(Ab + f * 2048 + aoff + sw0);
      a[f][1] = *(const v4i*)(Ab + f * 2048 + aoff + sw1);
    }
    asm volatile("s_barrier" ::: "memory");
    __builtin_amdgcn_s_setprio(1);
#pragma unroll
    for (int f = 0; f < 2; ++f)
#pragma unroll
      for (int n = 0; n < 4; ++n)
#pragma unroll
        for (int ks = 0; ks < 2; ++ks)
          acc[f][n] = MFMA_I8(a[f][ks], b[n][ks], acc[f][n], 0, 0, 0);
    __builtin_amdgcn_s_setprio(0);
    asm volatile("s_barrier" ::: "memory");

    // ---- phase 1: A f2,f3; stage B[kt+2] rows 0-127
#pragma unroll
    for (int f = 0; f < 2; ++f) {
      a[f][0] = *(const v4i*)(Ab + (2 + f) * 2048 + aoff + sw0);
      a[f][1] = *(const v4i*)(Ab + (2 + f) * 2048 + aoff + sw1);
    }
    if (pre) {
      gload16(gB + kfo, &Bl[p][0] + t * 16);
      gload16(gB + 64 * K_DIM + kfo, &Bl[p][0] + 8192 + t * 16);
    }
    asm volatile("s_barrier" ::: "memory");
    __builtin_amdgcn_s_setprio(1);
#pragma unroll
    for (int f = 0; f < 2; ++f)
#pragma unroll
      for (int n = 0; n < 4; ++n)
#pragma unroll
        for (int ks = 0; ks < 2; ++ks)
          acc[2 + f][n] = MFMA_I8(a[f][ks], b[n][ks], acc[2 + f][n], 0, 0, 0);
    __builtin_amdgcn_s_setprio(0);
    asm volatile("s_barrier" ::: "memory");

    // ---- phase 2: A f4,f5; stage B[kt+2] rows 128-255
#pragma unroll
    for (int f = 0; f < 2; ++f) {
      a[f][0] = *(const v4i*)(Ab + (4 + f) * 2048 + aoff + sw0);
      a[f][1] = *(const v4i*)(Ab + (4 + f) * 2048 + aoff + sw1);
    }
    if (pre) {
      gload16(gB + 128 * K_DIM + kfo, &Bl[p][0] + 16384 + t * 16);
      gload16(gB + 192 * K_DIM + kfo, &Bl[p][0] + 24576 + t * 16);
    }
    asm volatile("s_barrier" ::: "memory");
    __builtin_amdgcn_s_setprio(1);
#pragma unroll
    for (int f = 0; f < 2; ++f)
#pragma unroll
      for (int n = 0; n < 4; ++n)
#pragma unroll
        for (int ks = 0; ks < 2; ++ks)
          acc[4 + f][n] = MFMA_I8(a[f][ks], b[n][ks], acc[4 + f][n], 0, 0, 0);
    __builtin_amdgcn_s_setprio(0);
    asm volatile("s_barrier" ::: "memory");

    // ---- phase 3: A f6,f7; barrier; stage A[kt+2]; MFMA q3; vmcnt; barrier
#pragma unroll
    for (int f = 0; f < 2; ++f) {
      a[f][0] = *(const v4i*)(Ab + (6 + f) * 2048 + aoff + sw0);
      a[f][1] = *(const v4i*)(Ab + (6 + f) * 2048 + aoff + sw1);
    }
    asm volatile("s_barrier" ::: "memory");
    if (pre) {
      STAGE4(gA, &Al[p][0], kfo);
    }
    __builtin_amdgcn_s_setprio(1);
#pragma unroll
    for (int f = 0; f < 2; ++f)
#pragma unroll
      for (int n = 0; n < 4; ++n)
#pragma unroll
        for (int ks = 0; ks < 2; ++ks)
          acc[6 + f][n] = MFMA_I8(a[f][ks], b[n][ks], acc[6 + f][n], 0, 0, 0);
    __builtin_amdgcn_s_setprio(0);
    if (pre) {
      asm volatile("s_waitcnt vmcnt(8)" ::: "memory");
    } else {
      asm volatile("s_waitcnt vmcnt(0)" ::: "memory");
    }
    asm volatile("s_barrier" ::: "memory");
  }
#undef STAGE4

  __syncthreads();  // all LDS reads retired before tr aliases Al

  // ---- LDS-transpose epilogue: 4 chunks of 64 rows, tr stride 260 ----
  // Wave wm owns chunks 2wm, 2wm+1; chunk c uses acc f = (c&1)*4 .. +3.
  const long rowgw = bm * BM + wm * 128;  // wave's global row base
  const int colg0 = bn * BN + wn * 64;
#pragma unroll
  for (int c = 0; c < 4; ++c) {
    if ((c >> 1) == wm) {
      const int fb = (c & 1) * 4;
#pragma unroll
      for (int i = 0; i < 4; ++i) {
        const int f = fb + i;
        float as[4];
#pragma unroll
        for (int r = 0; r < 4; ++r) as[r] = asc[rowgw + f * 16 + kb * 4 + r];
#pragma unroll
        for (int j = 0; j < 4; ++j) {
          const float ws = wsc[colg0 + j * 16 + rl];
#pragma unroll
          for (int r = 0; r < 4; ++r)
            tr[(i * 16 + kb * 4 + r) * 260 + wn * 64 + j * 16 + rl] =
                (float)acc[f][j][r] * as[r] * ws;
        }
      }
    }
    __syncthreads();
    // 512 threads x 8 float4 nt stores; 64 lanes cover 1024B = 8 full lines
#pragma unroll
    for (int it = 0; it < 8; ++it) {
      const int idx = t + it * 512;   // 0..4095
      const int rl2 = idx >> 6;       // local row 0..63
      const int c4 = (idx & 63) * 4;  // col in floats 0..252
      const float4_t val = *(const float4_t*)(tr + rl2 * 260 + c4);
      __builtin_nontemporal_store(
          val, (float4_t*)(C + (bm * BM + c * 64 + rl2) * (long)N_DIM + bn * BN + c4));
    }
    if (c < 3) __syncthreads();  // tr reused by next chunk
  }
}

// ---------------------------------------------------------------------------
extern "C" void kernel_launch(void* const* d_in, const int* in_sizes, int n_in,
                              void* d_out, int out_size, void* d_ws, size_t ws_size,
                              hipStream_t stream) {
  const float* x = (const float*)d_in[0];  // [8,8192,1024] f32
  const float* w = (const float*)d_in[1];  // [1024,1024] f32
  float* out = (float*)d_out;              // [8,8192,1024] f32
  const int M = in_sizes[0] / K_DIM;       // 65536

  int8_t* qx = (int8_t*)d_ws;
  int8_t* qw = qx + (size_t)M * K_DIM;
  float* ascale = (float*)(qw + (size_t)N_DIM * K_DIM);
  float* wscale = ascale + M;

  fwht_quant_kernel<<<(M + 3) / 4, 256, 0, stream>>>(x, qx, ascale, M);
  wquant_kernel<<<N_DIM / 4, 256, 0, stream>>>(w, qw, wscale);
  gemm_i8_kernel<<<(M / BM) * (N_DIM / BN), 512, 0, stream>>>(qx, qw, ascale, wscale, out, M);
}